// Round 10
// baseline (410.299 us; speedup 1.0000x reference)
//
#include <hip/hip_runtime.h>

#define NN 100000
#define NE 1600000

#define SCAN_ELEMS 1024
#define SCAN_NB ((NN + SCAN_ELEMS - 1) / SCAN_ELEMS)   // 98

#define BNODES 256                       // nodes per sort bucket
#define NBUCK ((NN + BNODES - 1) / BNODES)  // 391
#define TILE 4096                        // edges per bin tile
#define NTILE ((NE + TILE - 1) / TILE)   // 391
#define CAP 5120                         // LDS sort capacity

typedef unsigned long long u64;
typedef unsigned short ushort_t;

// float -> bf16, round-to-nearest-even (values finite here)
__device__ __forceinline__ ushort_t f2bf(float f) {
    unsigned u = __float_as_uint(f);
    u += 0x7fffu + ((u >> 16) & 1u);
    return (ushort_t)(u >> 16);
}
__device__ __forceinline__ float bf2f(ushort_t b) {
    return __uint_as_float(((unsigned)b) << 16);
}

// ---------------- node-degree histogram + scan -> offsets ----------------

__global__ __launch_bounds__(256) void hist_kernel(const int* __restrict__ dst,
                                                   int* __restrict__ deg) {
    int e4 = (blockIdx.x * 256 + threadIdx.x) * 4;
    if (e4 >= NE) return;
    int4 d = *reinterpret_cast<const int4*>(dst + e4);
    atomicAdd(&deg[d.x], 1);
    atomicAdd(&deg[d.y], 1);
    atomicAdd(&deg[d.z], 1);
    atomicAdd(&deg[d.w], 1);
}

__global__ __launch_bounds__(256) void scan_pass1(const int* __restrict__ deg,
                                                  int* __restrict__ bsum) {
    int t = threadIdx.x;
    int i4 = blockIdx.x * SCAN_ELEMS + t * 4;
    int s = 0;
    if (i4 < NN) {
        int4 v = *reinterpret_cast<const int4*>(deg + i4);
        s = v.x + v.y + v.z + v.w;
    }
    __shared__ int red[256];
    red[t] = s;
    __syncthreads();
    for (int off = 128; off > 0; off >>= 1) {
        if (t < off) red[t] += red[t + off];
        __syncthreads();
    }
    if (t == 0) bsum[blockIdx.x] = red[0];
}

__global__ __launch_bounds__(128) void scan_pass2(int* __restrict__ bsum,
                                                  int* __restrict__ offsets) {
    int t = threadIdx.x;
    int v = (t < SCAN_NB) ? bsum[t] : 0;
    __shared__ int tmp[128];
    tmp[t] = v;
    __syncthreads();
    for (int off = 1; off < 128; off <<= 1) {
        int u = (t >= off) ? tmp[t - off] : 0;
        __syncthreads();
        tmp[t] += u;
        __syncthreads();
    }
    if (t < SCAN_NB) bsum[t] = tmp[t] - v;
    if (t == SCAN_NB - 1) offsets[NN] = tmp[t];
}

__global__ __launch_bounds__(256) void scan_pass3(const int* __restrict__ deg,
                                                  const int* __restrict__ bsum,
                                                  int* __restrict__ offsets) {
    int t = threadIdx.x;
    int i4 = blockIdx.x * SCAN_ELEMS + t * 4;
    int4 v = make_int4(0, 0, 0, 0);
    if (i4 < NN) v = *reinterpret_cast<const int4*>(deg + i4);
    int s = v.x + v.y + v.z + v.w;
    __shared__ int tmp[256];
    tmp[t] = s;
    __syncthreads();
    for (int off = 1; off < 256; off <<= 1) {
        int u = (t >= off) ? tmp[t - off] : 0;
        __syncthreads();
        tmp[t] += u;
        __syncthreads();
    }
    if (i4 < NN) {
        int base = bsum[blockIdx.x] + tmp[t] - s;
        int4 o;
        o.x = base;
        o.y = o.x + v.x;
        o.z = o.y + v.y;
        o.w = o.z + v.z;
        *reinterpret_cast<int4*>(offsets + i4) = o;
    }
}

__global__ __launch_bounds__(512) void initw_kernel(const int* __restrict__ offsets,
                                                    int* __restrict__ wcur) {
    int t = threadIdx.x;
    if (t < NBUCK) wcur[t] = offsets[t << 8];
}

// ---------------- phase A: bin edges into 391 buckets, coalesced writes ----

__global__ __launch_bounds__(256) void bin_kernel(const int* __restrict__ src,
                                                  const int* __restrict__ dst,
                                                  const float* __restrict__ w,
                                                  int* __restrict__ wcur,
                                                  u64* __restrict__ rec) {
    __shared__ int cnt[512];
    __shared__ int base_l[512];
    __shared__ int gbase[NBUCK];
    __shared__ int lofs[NBUCK];
    __shared__ int scan2[256];
    __shared__ u64 stage[TILE];
    __shared__ unsigned short stage_b[TILE];

    int t = threadIdx.x;
    cnt[t] = 0;
    cnt[t + 256] = 0;
    for (int b = t; b < NBUCK; b += 256) lofs[b] = 0;   // strided: NBUCK > 256
    __syncthreads();

    int e0 = blockIdx.x * TILE + t * 16;
    bool valid = e0 < NE;
    int d[16], s[16];
    float ww[16];
    if (valid) {
#pragma unroll
        for (int q = 0; q < 4; ++q) {
            int4 dv = *reinterpret_cast<const int4*>(dst + e0 + q * 4);
            int4 sv = *reinterpret_cast<const int4*>(src + e0 + q * 4);
            float4 wv = *reinterpret_cast<const float4*>(w + e0 + q * 4);
            d[q * 4 + 0] = dv.x; d[q * 4 + 1] = dv.y; d[q * 4 + 2] = dv.z; d[q * 4 + 3] = dv.w;
            s[q * 4 + 0] = sv.x; s[q * 4 + 1] = sv.y; s[q * 4 + 2] = sv.z; s[q * 4 + 3] = sv.w;
            ww[q * 4 + 0] = wv.x; ww[q * 4 + 1] = wv.y; ww[q * 4 + 2] = wv.z; ww[q * 4 + 3] = wv.w;
        }
#pragma unroll
        for (int i = 0; i < 16; ++i) atomicAdd(&cnt[d[i] >> 8], 1);
    }
    __syncthreads();

    int pair = cnt[2 * t] + cnt[2 * t + 1];
    scan2[t] = pair;
    __syncthreads();
    for (int off = 1; off < 256; off <<= 1) {
        int u = (t >= off) ? scan2[t - off] : 0;
        __syncthreads();
        scan2[t] += u;
        __syncthreads();
    }
    int excl = scan2[t] - pair;
    base_l[2 * t]     = excl;
    base_l[2 * t + 1] = excl + cnt[2 * t];
    for (int b = t; b < NBUCK; b += 256)
        gbase[b] = atomicAdd(&wcur[b], cnt[b]);
    __syncthreads();

    if (valid) {
#pragma unroll
        for (int i = 0; i < 16; ++i) {
            int b = d[i] >> 8;
            int p = base_l[b] + atomicAdd(&lofs[b], 1);
            u64 hi = (u64)(unsigned)(s[i] | ((d[i] & 0xFF) << 17));
            stage[p]   = (hi << 32) | (u64)(unsigned)__float_as_int(ww[i]);
            stage_b[p] = (unsigned short)b;
        }
    }
    __syncthreads();

    int tot = scan2[255];
    for (int i = t; i < tot; i += 256) {
        int b = stage_b[i];
        rec[gbase[b] + (i - base_l[b])] = stage[i];
    }
}

// ---------------- phase B: per-bucket LDS counting sort -> CSR --------------

__global__ __launch_bounds__(256) void sort_kernel(const u64* __restrict__ rec,
                                                   const int* __restrict__ offsets,
                                                   int2* __restrict__ csr) {
    __shared__ int2 outb[CAP];
    __shared__ int off_l[BNODES];
    __shared__ int ctr[BNODES];

    int b = blockIdx.x;
    int node0 = b << 8;
    int t = threadIdx.x;
    int gbase = offsets[node0];
    int gend  = offsets[min(node0 + BNODES, NN)];
    int cntb  = gend - gbase;

    if (t < BNODES) {
        off_l[t] = offsets[min(node0 + t, NN)] - gbase;
        ctr[t] = 0;
    }
    __syncthreads();

    if (cntb <= CAP) {
        for (int i = t; i < cntb; i += 256) {
            u64 r = rec[gbase + i];
            unsigned hi = (unsigned)(r >> 32);
            int n = (int)(hi >> 17);
            int slot = off_l[n] + atomicAdd(&ctr[n], 1);
            outb[slot] = make_int2((int)(hi & 0x1FFFF), (int)(unsigned)r);
        }
        __syncthreads();
        for (int i = t; i < cntb; i += 256)
            csr[gbase + i] = outb[i];
    } else {
        for (int i = t; i < cntb; i += 256) {
            u64 r = rec[gbase + i];
            unsigned hi = (unsigned)(r >> 32);
            int n = (int)(hi >> 17);
            int slot = off_l[n] + atomicAdd(&ctr[n], 1);
            csr[gbase + slot] = make_int2((int)(hi & 0x1FFFF), (int)(unsigned)r);
        }
    }
}

// ---------------- dense GEMM: S[N,64] = bf16(X[N,K] @ W[K,64]) ----------------
// Both operands in LDS. X tile (32 rows) copied coalesced 16B/lane; W
// transposed [64][K+1] (lane=col reads: bank (lane+k)%32, 2-way = free).
// Compute: lane=col, 8 rows/wave; per 4-k: 4 broadcast w reads + 8 uniform
// ds_read_b128 x reads + 32 v_fmac. No scalar pipe, no multi-line VMEM.
// Store bf16: 64 lanes x 2B contiguous = 128B/row.

template <int K>
__global__ __launch_bounds__(256) void gemm_kernel(const float* __restrict__ X,
                                                   const float* __restrict__ W,
                                                   ushort_t* __restrict__ S) {
    __shared__ float Wt[64][K + 1];
    __shared__ float Xs[32][K];

    int t = threadIdx.x;
    for (int idx = t; idx < K * 64; idx += 256) {
        int k = idx >> 6, c = idx & 63;
        Wt[c][k] = W[idx];
    }
    const float4* xg = reinterpret_cast<const float4*>(X + (size_t)blockIdx.x * 32 * K);
    float4* xs = reinterpret_cast<float4*>(&Xs[0][0]);
#pragma unroll
    for (int i = t; i < 32 * K / 4; i += 256)
        xs[i] = xg[i];                     // coalesced 16B/lane, 1KB/wave-instr
    __syncthreads();

    int wave = t >> 6;
    int lane = t & 63;
    int rbase = wave * 8;

    float acc[8] = {0.f, 0.f, 0.f, 0.f, 0.f, 0.f, 0.f, 0.f};

#pragma unroll 4
    for (int kk = 0; kk < K; kk += 4) {
        float w0 = Wt[lane][kk];
        float w1 = Wt[lane][kk + 1];
        float w2 = Wt[lane][kk + 2];
        float w3 = Wt[lane][kk + 3];
#pragma unroll
        for (int r = 0; r < 8; ++r) {
            float4 xv = *reinterpret_cast<const float4*>(&Xs[rbase + r][kk]);  // uniform -> broadcast
            acc[r] = fmaf(xv.x, w0, fmaf(xv.y, w1, fmaf(xv.z, w2, fmaf(xv.w, w3, acc[r]))));
        }
    }

    int row0 = blockIdx.x * 32 + rbase;    // NN % 32 == 0, grid exact
#pragma unroll
    for (int r = 0; r < 8; ++r)
        S[(size_t)(row0 + r) * 64 + lane] = f2bf(acc[r]);
}

// ---------------- SPMM gather (bf16 S table: 128B/edge, 12.8MB footprint) ----

template <bool RELU>
__global__ __launch_bounds__(256) void spmm_kernel(const int2* __restrict__ csr,
                                                   const int* __restrict__ offsets,
                                                   const ushort_t* __restrict__ S,
                                                   const float* __restrict__ bias,
                                                   float* __restrict__ out, int N) {
    int wave = threadIdx.x >> 6;
    int lane = threadIdx.x & 63;
    int row  = blockIdx.x * 4 + wave;
    if (row >= N) return;

    int beg = offsets[row];
    int end = offsets[row + 1];
    float acc = 0.f;
    int e = beg;
    for (; e + 4 <= end; e += 4) {
        int2 e0 = csr[e],     e1 = csr[e + 1];
        int2 e2 = csr[e + 2], e3 = csr[e + 3];
        float v0 = bf2f(S[e0.x * 64 + lane]);
        float v1 = bf2f(S[e1.x * 64 + lane]);
        float v2 = bf2f(S[e2.x * 64 + lane]);
        float v3 = bf2f(S[e3.x * 64 + lane]);
        acc += __int_as_float(e0.y) * v0;
        acc += __int_as_float(e1.y) * v1;
        acc += __int_as_float(e2.y) * v2;
        acc += __int_as_float(e3.y) * v3;
    }
    for (; e < end; ++e) {
        int2 ee = csr[e];
        acc += __int_as_float(ee.y) * bf2f(S[ee.x * 64 + lane]);
    }
    float v = acc + bias[lane];
    if (RELU) v = fmaxf(v, 0.f);
    out[(size_t)row * 64 + lane] = v;
}

// ---------------- launch ----------------

extern "C" void kernel_launch(void* const* d_in, const int* in_sizes, int n_in,
                              void* d_out, int out_size, void* d_ws, size_t ws_size,
                              hipStream_t stream) {
    const float* features = (const float*)d_in[0];
    const int*   src      = (const int*)d_in[1];
    const int*   dst      = (const int*)d_in[2];
    const float* ew       = (const float*)d_in[3];
    const float* W1       = (const float*)d_in[4];
    const float* b1       = (const float*)d_in[5];
    const float* W2       = (const float*)d_in[6];
    const float* b2       = (const float*)d_in[7];
    const float* W3       = (const float*)d_in[8];
    const float* b3       = (const float*)d_in[9];
    float*       out      = (float*)d_out;

    float*    s_f32  = (float*)d_ws;                     // NN*64 region (S lives here as bf16)
    ushort_t* s_bf   = (ushort_t*)d_ws;
    float*    h_buf  = s_f32 + (size_t)NN * 64;          // NN*64 f32 (rec aliases)
    int*   deg     = (int*)(h_buf + (size_t)NN * 64);    // NN
    int*   offsets = deg + NN;                           // NN+4
    int*   bsum    = offsets + NN + 4;                   // 128
    int*   wcur    = bsum + 128;                         // NBUCK (pad 512)
    int2*  csr     = (int2*)(wcur + 512);                // NE packed records
    u64*   rec     = (u64*)h_buf;                        // NE binned records

    (void)hipMemsetAsync(deg, 0, NN * sizeof(int), stream);
    hist_kernel<<<(NE / 4 + 255) / 256, 256, 0, stream>>>(dst, deg);
    scan_pass1<<<SCAN_NB, 256, 0, stream>>>(deg, bsum);
    scan_pass2<<<1, 128, 0, stream>>>(bsum, offsets);
    scan_pass3<<<SCAN_NB, 256, 0, stream>>>(deg, bsum, offsets);
    initw_kernel<<<1, 512, 0, stream>>>(offsets, wcur);
    bin_kernel<<<NTILE, 256, 0, stream>>>(src, dst, ew, wcur, rec);
    sort_kernel<<<NBUCK, 256, 0, stream>>>(rec, offsets, csr);

    int grid_gemm = NN / 32;            // 3125, exact: 32 rows per block
    int grid_rows = (NN + 3) / 4;
    gemm_kernel<128><<<grid_gemm, 256, 0, stream>>>(features, W1, s_bf);
    spmm_kernel<true><<<grid_rows, 256, 0, stream>>>(csr, offsets, s_bf, b1, h_buf, NN);
    gemm_kernel<64><<<grid_gemm, 256, 0, stream>>>(h_buf, W2, s_bf);
    spmm_kernel<true><<<grid_rows, 256, 0, stream>>>(csr, offsets, s_bf, b2, h_buf, NN);
    gemm_kernel<64><<<grid_gemm, 256, 0, stream>>>(h_buf, W3, s_bf);
    spmm_kernel<false><<<grid_rows, 256, 0, stream>>>(csr, offsets, s_bf, b3, out, NN);
}

// Round 12
// 324.434 us; speedup vs baseline: 1.2647x; 1.2647x over previous
//
#include <hip/hip_runtime.h>

#define NN 100000
#define NE 1600000

#define BNODES 256                          // nodes per sort bucket
#define NBUCK ((NN + BNODES - 1) / BNODES)  // 391
#define TILE 4096                           // edges per bin tile
#define NTILE ((NE + TILE - 1) / TILE)      // 391
#define CAP 5120                            // LDS sort capacity
#define HTILE 4096                          // edges per bucket_hist block (256 thr x 16)
#define NHB ((NE + HTILE - 1) / HTILE)      // 391

typedef unsigned long long u64;
typedef unsigned short ushort_t;

// float -> bf16 RNE
__device__ __forceinline__ ushort_t f2bf(float f) {
    unsigned u = __float_as_uint(f);
    u += 0x7fffu + ((u >> 16) & 1u);
    return (ushort_t)(u >> 16);
}
__device__ __forceinline__ float bf2f(ushort_t b) {
    return __uint_as_float(((unsigned)b) << 16);
}

// ---------------- bucket histogram (391 counters, LDS-staged) ----------------

__global__ __launch_bounds__(256) void bucket_hist(const int* __restrict__ dst,
                                                   int* __restrict__ gcnt) {
    __shared__ int cnt[NBUCK];
    int t = threadIdx.x;
    for (int b = t; b < NBUCK; b += 256) cnt[b] = 0;
    __syncthreads();
    int e0 = blockIdx.x * HTILE + t * 16;   // block covers exactly HTILE=4096 edges
    if (e0 < NE) {                          // NE % 16 == 0 -> all-or-nothing per thread
#pragma unroll
        for (int q = 0; q < 4; ++q) {
            int4 d = *reinterpret_cast<const int4*>(dst + e0 + q * 4);
            atomicAdd(&cnt[d.x >> 8], 1);
            atomicAdd(&cnt[d.y >> 8], 1);
            atomicAdd(&cnt[d.z >> 8], 1);
            atomicAdd(&cnt[d.w >> 8], 1);
        }
    }
    __syncthreads();
    for (int b = t; b < NBUCK; b += 256)
        if (cnt[b]) atomicAdd(&gcnt[b], cnt[b]);
}

// one block: exclusive-scan bucket counts -> bucket bases; init wcur; offsets[NN]
__global__ __launch_bounds__(512) void bucket_scan(const int* __restrict__ gcnt,
                                                   int* __restrict__ bbase,
                                                   int* __restrict__ wcur,
                                                   int* __restrict__ offsets) {
    __shared__ int tmp[512];
    int t = threadIdx.x;
    int v = (t < NBUCK) ? gcnt[t] : 0;
    tmp[t] = v;
    __syncthreads();
    for (int off = 1; off < 512; off <<= 1) {
        int u = (t >= off) ? tmp[t - off] : 0;
        __syncthreads();
        tmp[t] += u;
        __syncthreads();
    }
    if (t < NBUCK) {
        int base = tmp[t] - v;
        bbase[t] = base;
        wcur[t]  = base;
    }
    if (t == NBUCK - 1) bbase[NBUCK] = tmp[t];
    if (t == 0) offsets[NN] = NE;
}

// ---------------- phase A: bin edges into 391 buckets, coalesced writes ----

__global__ __launch_bounds__(256) void bin_kernel(const int* __restrict__ src,
                                                  const int* __restrict__ dst,
                                                  const float* __restrict__ w,
                                                  int* __restrict__ wcur,
                                                  u64* __restrict__ rec) {
    __shared__ int cnt[512];
    __shared__ int base_l[512];
    __shared__ int gbase[NBUCK];
    __shared__ int lofs[NBUCK];
    __shared__ int scan2[256];
    __shared__ u64 stage[TILE];
    __shared__ unsigned short stage_b[TILE];

    int t = threadIdx.x;
    cnt[t] = 0;
    cnt[t + 256] = 0;
    for (int b = t; b < NBUCK; b += 256) lofs[b] = 0;   // strided: NBUCK > 256
    __syncthreads();

    int e0 = blockIdx.x * TILE + t * 16;
    bool valid = e0 < NE;
    int d[16], s[16];
    float ww[16];
    if (valid) {
#pragma unroll
        for (int q = 0; q < 4; ++q) {
            int4 dv = *reinterpret_cast<const int4*>(dst + e0 + q * 4);
            int4 sv = *reinterpret_cast<const int4*>(src + e0 + q * 4);
            float4 wv = *reinterpret_cast<const float4*>(w + e0 + q * 4);
            d[q * 4 + 0] = dv.x; d[q * 4 + 1] = dv.y; d[q * 4 + 2] = dv.z; d[q * 4 + 3] = dv.w;
            s[q * 4 + 0] = sv.x; s[q * 4 + 1] = sv.y; s[q * 4 + 2] = sv.z; s[q * 4 + 3] = sv.w;
            ww[q * 4 + 0] = wv.x; ww[q * 4 + 1] = wv.y; ww[q * 4 + 2] = wv.z; ww[q * 4 + 3] = wv.w;
        }
#pragma unroll
        for (int i = 0; i < 16; ++i) atomicAdd(&cnt[d[i] >> 8], 1);
    }
    __syncthreads();

    int pair = cnt[2 * t] + cnt[2 * t + 1];
    scan2[t] = pair;
    __syncthreads();
    for (int off = 1; off < 256; off <<= 1) {
        int u = (t >= off) ? scan2[t - off] : 0;
        __syncthreads();
        scan2[t] += u;
        __syncthreads();
    }
    int excl = scan2[t] - pair;
    base_l[2 * t]     = excl;
    base_l[2 * t + 1] = excl + cnt[2 * t];
    for (int b = t; b < NBUCK; b += 256)
        gbase[b] = atomicAdd(&wcur[b], cnt[b]);
    __syncthreads();

    if (valid) {
#pragma unroll
        for (int i = 0; i < 16; ++i) {
            int b = d[i] >> 8;
            int p = base_l[b] + atomicAdd(&lofs[b], 1);
            u64 hi = (u64)(unsigned)(s[i] | ((d[i] & 0xFF) << 17));
            stage[p]   = (hi << 32) | (u64)(unsigned)__float_as_int(ww[i]);
            stage_b[p] = (unsigned short)b;
        }
    }
    __syncthreads();

    int tot = scan2[255];
    for (int i = t; i < tot; i += 256) {
        int b = stage_b[i];
        rec[gbase[b] + (i - base_l[b])] = stage[i];
    }
}

// ---------------- phase B: per-bucket count+scan+sort -> offsets & CSR ------

__global__ __launch_bounds__(256) void sort_kernel(const u64* __restrict__ rec,
                                                   const int* __restrict__ bbase,
                                                   int* __restrict__ offsets,
                                                   int2* __restrict__ csr) {
    __shared__ int2 outb[CAP];
    __shared__ int scanb[BNODES];
    __shared__ int off_l[BNODES];
    __shared__ int ctr[BNODES];

    int b = blockIdx.x;
    int node0 = b << 8;
    int t = threadIdx.x;
    int gbase = bbase[b];
    int gend  = bbase[b + 1];
    int cntb  = gend - gbase;

    ctr[t] = 0;          // BNODES == 256 == blockDim
    __syncthreads();

    // pass 1: per-node degree within bucket
    for (int i = t; i < cntb; i += 256) {
        u64 r = rec[gbase + i];
        int n = (int)((unsigned)(r >> 32) >> 17);
        atomicAdd(&ctr[n], 1);
    }
    __syncthreads();

    // exclusive scan of 256 degrees
    int v = ctr[t];
    scanb[t] = v;
    __syncthreads();
    for (int off = 1; off < 256; off <<= 1) {
        int u = (t >= off) ? scanb[t - off] : 0;
        __syncthreads();
        scanb[t] += u;
        __syncthreads();
    }
    int excl = scanb[t] - v;
    off_l[t] = excl;
    ctr[t] = 0;
    int node = node0 + t;
    if (node < NN) offsets[node] = gbase + excl;   // coalesced offsets write
    __syncthreads();

    // pass 2: sort records into per-node slots
    if (cntb <= CAP) {
        for (int i = t; i < cntb; i += 256) {
            u64 r = rec[gbase + i];
            unsigned hi = (unsigned)(r >> 32);
            int n = (int)(hi >> 17);
            int slot = off_l[n] + atomicAdd(&ctr[n], 1);
            outb[slot] = make_int2((int)(hi & 0x1FFFF), (int)(unsigned)r);
        }
        __syncthreads();
        for (int i = t; i < cntb; i += 256)
            csr[gbase + i] = outb[i];
    } else {
        // overflow fallback (never for this input)
        for (int i = t; i < cntb; i += 256) {
            u64 r = rec[gbase + i];
            unsigned hi = (unsigned)(r >> 32);
            int n = (int)(hi >> 17);
            int slot = off_l[n] + atomicAdd(&ctr[n], 1);
            csr[gbase + slot] = make_int2((int)(hi & 0x1FFFF), (int)(unsigned)r);
        }
    }
}

// ---------------- dense GEMM: S[N,64] = bf16(X[N,K] @ W[K,64]) --------------

template <int K>
__global__ __launch_bounds__(256) void gemm_kernel(const float* __restrict__ X,
                                                   const float* __restrict__ W,
                                                   ushort_t* __restrict__ S) {
    __shared__ float Wt[64][K + 1];
    __shared__ float Xs[32][K];

    int t = threadIdx.x;
    for (int idx = t; idx < K * 64; idx += 256) {
        int k = idx >> 6, c = idx & 63;
        Wt[c][k] = W[idx];
    }
    const float4* xg = reinterpret_cast<const float4*>(X + (size_t)blockIdx.x * 32 * K);
    float4* xs = reinterpret_cast<float4*>(&Xs[0][0]);
#pragma unroll
    for (int i = t; i < 32 * K / 4; i += 256)
        xs[i] = xg[i];
    __syncthreads();

    int wave = t >> 6;
    int lane = t & 63;
    int rbase = wave * 8;

    float acc[8] = {0.f, 0.f, 0.f, 0.f, 0.f, 0.f, 0.f, 0.f};

#pragma unroll 4
    for (int kk = 0; kk < K; kk += 4) {
        float w0 = Wt[lane][kk];
        float w1 = Wt[lane][kk + 1];
        float w2 = Wt[lane][kk + 2];
        float w3 = Wt[lane][kk + 3];
#pragma unroll
        for (int r = 0; r < 8; ++r) {
            float4 xv = *reinterpret_cast<const float4*>(&Xs[rbase + r][kk]);
            acc[r] = fmaf(xv.x, w0, fmaf(xv.y, w1, fmaf(xv.z, w2, fmaf(xv.w, w3, acc[r]))));
        }
    }

    int row0 = blockIdx.x * 32 + rbase;    // NN % 32 == 0
#pragma unroll
    for (int r = 0; r < 8; ++r)
        S[(size_t)(row0 + r) * 64 + lane] = f2bf(acc[r]);
}

// ---------------- SPMM gather (bf16 S; 8 gathers in flight, 2 acc chains) ---

template <bool RELU>
__global__ __launch_bounds__(256) void spmm_kernel(const int2* __restrict__ csr,
                                                   const int* __restrict__ offsets,
                                                   const ushort_t* __restrict__ S,
                                                   const float* __restrict__ bias,
                                                   float* __restrict__ out, int N) {
    int wave = threadIdx.x >> 6;
    int lane = threadIdx.x & 63;
    int row  = blockIdx.x * 4 + wave;
    if (row >= N) return;

    int beg = offsets[row];
    int end = offsets[row + 1];
    float acc0 = 0.f, acc1 = 0.f;
    int e = beg;
    for (; e + 8 <= end; e += 8) {
        int2 c0 = csr[e],     c1 = csr[e + 1], c2 = csr[e + 2], c3 = csr[e + 3];
        int2 c4 = csr[e + 4], c5 = csr[e + 5], c6 = csr[e + 6], c7 = csr[e + 7];
        float v0 = bf2f(S[c0.x * 64 + lane]);
        float v1 = bf2f(S[c1.x * 64 + lane]);
        float v2 = bf2f(S[c2.x * 64 + lane]);
        float v3 = bf2f(S[c3.x * 64 + lane]);
        float v4 = bf2f(S[c4.x * 64 + lane]);
        float v5 = bf2f(S[c5.x * 64 + lane]);
        float v6 = bf2f(S[c6.x * 64 + lane]);
        float v7 = bf2f(S[c7.x * 64 + lane]);
        acc0 = fmaf(__int_as_float(c0.y), v0, acc0);
        acc1 = fmaf(__int_as_float(c1.y), v1, acc1);
        acc0 = fmaf(__int_as_float(c2.y), v2, acc0);
        acc1 = fmaf(__int_as_float(c3.y), v3, acc1);
        acc0 = fmaf(__int_as_float(c4.y), v4, acc0);
        acc1 = fmaf(__int_as_float(c5.y), v5, acc1);
        acc0 = fmaf(__int_as_float(c6.y), v6, acc0);
        acc1 = fmaf(__int_as_float(c7.y), v7, acc1);
    }
    for (; e + 2 <= end; e += 2) {
        int2 c0 = csr[e], c1 = csr[e + 1];
        float v0 = bf2f(S[c0.x * 64 + lane]);
        float v1 = bf2f(S[c1.x * 64 + lane]);
        acc0 = fmaf(__int_as_float(c0.y), v0, acc0);
        acc1 = fmaf(__int_as_float(c1.y), v1, acc1);
    }
    if (e < end) {
        int2 c0 = csr[e];
        acc0 = fmaf(__int_as_float(c0.y), bf2f(S[c0.x * 64 + lane]), acc0);
    }
    float v = acc0 + acc1 + bias[lane];
    if (RELU) v = fmaxf(v, 0.f);
    out[(size_t)row * 64 + lane] = v;
}

// ---------------- launch ----------------

extern "C" void kernel_launch(void* const* d_in, const int* in_sizes, int n_in,
                              void* d_out, int out_size, void* d_ws, size_t ws_size,
                              hipStream_t stream) {
    const float* features = (const float*)d_in[0];
    const int*   src      = (const int*)d_in[1];
    const int*   dst      = (const int*)d_in[2];
    const float* ew       = (const float*)d_in[3];
    const float* W1       = (const float*)d_in[4];
    const float* b1       = (const float*)d_in[5];
    const float* W2       = (const float*)d_in[6];
    const float* b2       = (const float*)d_in[7];
    const float* W3       = (const float*)d_in[8];
    const float* b3       = (const float*)d_in[9];
    float*       out      = (float*)d_out;

    float*    s_f32  = (float*)d_ws;                     // NN*64 region (S as bf16)
    ushort_t* s_bf   = (ushort_t*)d_ws;
    float*    h_buf  = s_f32 + (size_t)NN * 64;          // NN*64 f32 (rec aliases)
    int*   offsets = (int*)(h_buf + (size_t)NN * 64);    // NN+4
    int*   gcnt    = offsets + NN + 4;                   // NBUCK (pad 512)
    int*   bbase   = gcnt + 512;                         // NBUCK+1 (pad 512)
    int*   wcur    = bbase + 512;                        // NBUCK (pad 512)
    int2*  csr     = (int2*)(wcur + 512);                // NE packed records
    u64*   rec     = (u64*)h_buf;                        // NE binned records

    (void)hipMemsetAsync(gcnt, 0, NBUCK * sizeof(int), stream);
    bucket_hist<<<NHB, 256, 0, stream>>>(dst, gcnt);
    bucket_scan<<<1, 512, 0, stream>>>(gcnt, bbase, wcur, offsets);
    bin_kernel<<<NTILE, 256, 0, stream>>>(src, dst, ew, wcur, rec);
    sort_kernel<<<NBUCK, 256, 0, stream>>>(rec, bbase, offsets, csr);

    int grid_gemm = NN / 32;            // 3125
    int grid_rows = (NN + 3) / 4;
    gemm_kernel<128><<<grid_gemm, 256, 0, stream>>>(features, W1, s_bf);
    spmm_kernel<true><<<grid_rows, 256, 0, stream>>>(csr, offsets, s_bf, b1, h_buf, NN);
    gemm_kernel<64><<<grid_gemm, 256, 0, stream>>>(h_buf, W2, s_bf);
    spmm_kernel<true><<<grid_rows, 256, 0, stream>>>(csr, offsets, s_bf, b2, h_buf, NN);
    gemm_kernel<64><<<grid_gemm, 256, 0, stream>>>(h_buf, W3, s_bf);
    spmm_kernel<false><<<grid_rows, 256, 0, stream>>>(csr, offsets, s_bf, b3, out, NN);
}

// Round 13
// 269.688 us; speedup vs baseline: 1.5214x; 1.2030x over previous
//
#include <hip/hip_runtime.h>

#define NN 100000
#define NE 1600000

#define BNODES 256                          // nodes per sort bucket
#define NBUCK ((NN + BNODES - 1) / BNODES)  // 391
#define TILE 4096                           // edges per bin tile
#define NTILE ((NE + TILE - 1) / TILE)      // 391
#define CAP 5120                            // LDS sort capacity
#define HTILE 4096                          // edges per bucket_hist block
#define NHB ((NE + HTILE - 1) / HTILE)      // 391

typedef unsigned long long u64;
typedef unsigned short ushort_t;
typedef __attribute__((ext_vector_type(8))) short bf16x8;
typedef __attribute__((ext_vector_type(4))) float f32x4;

// float -> bf16 RNE
__device__ __forceinline__ ushort_t f2bf(float f) {
    unsigned u = __float_as_uint(f);
    u += 0x7fffu + ((u >> 16) & 1u);
    return (ushort_t)(u >> 16);
}
__device__ __forceinline__ float bf2f(ushort_t b) {
    return __uint_as_float(((unsigned)b) << 16);
}

// ---------------- bucket histogram (391 counters, LDS-staged) ----------------

__global__ __launch_bounds__(256) void bucket_hist(const int* __restrict__ dst,
                                                   int* __restrict__ gcnt) {
    __shared__ int cnt[NBUCK];
    int t = threadIdx.x;
    for (int b = t; b < NBUCK; b += 256) cnt[b] = 0;
    __syncthreads();
    int e0 = blockIdx.x * HTILE + t * 16;
    if (e0 < NE) {
#pragma unroll
        for (int q = 0; q < 4; ++q) {
            int4 d = *reinterpret_cast<const int4*>(dst + e0 + q * 4);
            atomicAdd(&cnt[d.x >> 8], 1);
            atomicAdd(&cnt[d.y >> 8], 1);
            atomicAdd(&cnt[d.z >> 8], 1);
            atomicAdd(&cnt[d.w >> 8], 1);
        }
    }
    __syncthreads();
    for (int b = t; b < NBUCK; b += 256)
        if (cnt[b]) atomicAdd(&gcnt[b], cnt[b]);
}

__global__ __launch_bounds__(512) void bucket_scan(const int* __restrict__ gcnt,
                                                   int* __restrict__ bbase,
                                                   int* __restrict__ wcur,
                                                   int* __restrict__ offsets) {
    __shared__ int tmp[512];
    int t = threadIdx.x;
    int v = (t < NBUCK) ? gcnt[t] : 0;
    tmp[t] = v;
    __syncthreads();
    for (int off = 1; off < 512; off <<= 1) {
        int u = (t >= off) ? tmp[t - off] : 0;
        __syncthreads();
        tmp[t] += u;
        __syncthreads();
    }
    if (t < NBUCK) {
        int base = tmp[t] - v;
        bbase[t] = base;
        wcur[t]  = base;
    }
    if (t == NBUCK - 1) bbase[NBUCK] = tmp[t];
    if (t == 0) offsets[NN] = NE;
}

// ---------------- phase A: bin edges into 391 buckets ----------------

__global__ __launch_bounds__(256) void bin_kernel(const int* __restrict__ src,
                                                  const int* __restrict__ dst,
                                                  const float* __restrict__ w,
                                                  int* __restrict__ wcur,
                                                  u64* __restrict__ rec) {
    __shared__ int cnt[512];
    __shared__ int base_l[512];
    __shared__ int gbase[NBUCK];
    __shared__ int lofs[NBUCK];
    __shared__ int scan2[256];
    __shared__ u64 stage[TILE];
    __shared__ unsigned short stage_b[TILE];

    int t = threadIdx.x;
    cnt[t] = 0;
    cnt[t + 256] = 0;
    for (int b = t; b < NBUCK; b += 256) lofs[b] = 0;   // strided: NBUCK > 256
    __syncthreads();

    int e0 = blockIdx.x * TILE + t * 16;
    bool valid = e0 < NE;
    int d[16], s[16];
    float ww[16];
    if (valid) {
#pragma unroll
        for (int q = 0; q < 4; ++q) {
            int4 dv = *reinterpret_cast<const int4*>(dst + e0 + q * 4);
            int4 sv = *reinterpret_cast<const int4*>(src + e0 + q * 4);
            float4 wv = *reinterpret_cast<const float4*>(w + e0 + q * 4);
            d[q * 4 + 0] = dv.x; d[q * 4 + 1] = dv.y; d[q * 4 + 2] = dv.z; d[q * 4 + 3] = dv.w;
            s[q * 4 + 0] = sv.x; s[q * 4 + 1] = sv.y; s[q * 4 + 2] = sv.z; s[q * 4 + 3] = sv.w;
            ww[q * 4 + 0] = wv.x; ww[q * 4 + 1] = wv.y; ww[q * 4 + 2] = wv.z; ww[q * 4 + 3] = wv.w;
        }
#pragma unroll
        for (int i = 0; i < 16; ++i) atomicAdd(&cnt[d[i] >> 8], 1);
    }
    __syncthreads();

    int pair = cnt[2 * t] + cnt[2 * t + 1];
    scan2[t] = pair;
    __syncthreads();
    for (int off = 1; off < 256; off <<= 1) {
        int u = (t >= off) ? scan2[t - off] : 0;
        __syncthreads();
        scan2[t] += u;
        __syncthreads();
    }
    int excl = scan2[t] - pair;
    base_l[2 * t]     = excl;
    base_l[2 * t + 1] = excl + cnt[2 * t];
    for (int b = t; b < NBUCK; b += 256)
        gbase[b] = atomicAdd(&wcur[b], cnt[b]);
    __syncthreads();

    if (valid) {
#pragma unroll
        for (int i = 0; i < 16; ++i) {
            int b = d[i] >> 8;
            int p = base_l[b] + atomicAdd(&lofs[b], 1);
            u64 hi = (u64)(unsigned)(s[i] | ((d[i] & 0xFF) << 17));
            stage[p]   = (hi << 32) | (u64)(unsigned)__float_as_int(ww[i]);
            stage_b[p] = (unsigned short)b;
        }
    }
    __syncthreads();

    int tot = scan2[255];
    for (int i = t; i < tot; i += 256) {
        int b = stage_b[i];
        rec[gbase[b] + (i - base_l[b])] = stage[i];
    }
}

// ---------------- phase B: per-bucket count+scan+sort -> offsets & CSR ------

__global__ __launch_bounds__(256) void sort_kernel(const u64* __restrict__ rec,
                                                   const int* __restrict__ bbase,
                                                   int* __restrict__ offsets,
                                                   int2* __restrict__ csr) {
    __shared__ int2 outb[CAP];
    __shared__ int scanb[BNODES];
    __shared__ int off_l[BNODES];
    __shared__ int ctr[BNODES];

    int b = blockIdx.x;
    int node0 = b << 8;
    int t = threadIdx.x;
    int gbase = bbase[b];
    int gend  = bbase[b + 1];
    int cntb  = gend - gbase;

    ctr[t] = 0;
    __syncthreads();

    for (int i = t; i < cntb; i += 256) {
        u64 r = rec[gbase + i];
        int n = (int)((unsigned)(r >> 32) >> 17);
        atomicAdd(&ctr[n], 1);
    }
    __syncthreads();

    int v = ctr[t];
    scanb[t] = v;
    __syncthreads();
    for (int off = 1; off < 256; off <<= 1) {
        int u = (t >= off) ? scanb[t - off] : 0;
        __syncthreads();
        scanb[t] += u;
        __syncthreads();
    }
    int excl = scanb[t] - v;
    off_l[t] = excl;
    ctr[t] = 0;
    int node = node0 + t;
    if (node < NN) offsets[node] = gbase + excl;
    __syncthreads();

    if (cntb <= CAP) {
        for (int i = t; i < cntb; i += 256) {
            u64 r = rec[gbase + i];
            unsigned hi = (unsigned)(r >> 32);
            int n = (int)(hi >> 17);
            int slot = off_l[n] + atomicAdd(&ctr[n], 1);
            outb[slot] = make_int2((int)(hi & 0x1FFFF), (int)(unsigned)r);
        }
        __syncthreads();
        for (int i = t; i < cntb; i += 256)
            csr[gbase + i] = outb[i];
    } else {
        for (int i = t; i < cntb; i += 256) {
            u64 r = rec[gbase + i];
            unsigned hi = (unsigned)(r >> 32);
            int n = (int)(hi >> 17);
            int slot = off_l[n] + atomicAdd(&ctr[n], 1);
            csr[gbase + slot] = make_int2((int)(hi & 0x1FFFF), (int)(unsigned)r);
        }
    }
}

// ---------------- W converter: W[K][64] f32 -> Wt[64][K] bf16 (once) --------
// blocks 0..7 -> W1(K=128), 8..11 -> W2(64), 12..15 -> W3(64); 1024 elems/blk

__global__ __launch_bounds__(256) void wconv_kernel(const float* __restrict__ W1,
                                                    const float* __restrict__ W2,
                                                    const float* __restrict__ W3,
                                                    ushort_t* __restrict__ wt1,
                                                    ushort_t* __restrict__ wt2,
                                                    ushort_t* __restrict__ wt3) {
    int b = blockIdx.x;
    const float* W; ushort_t* wt; int K, bl;
    if (b < 8)       { W = W1; wt = wt1; K = 128; bl = b; }
    else if (b < 12) { W = W2; wt = wt2; K = 64;  bl = b - 8; }
    else             { W = W3; wt = wt3; K = 64;  bl = b - 12; }
    int u = (bl * 256 + threadIdx.x) * 4;          // wt index: c*K + k, k%4==0
    if (u >= 64 * K) return;
    int c = u / K, k = u % K;
    ushort4 o;
    o.x = f2bf(W[(k + 0) * 64 + c]);
    o.y = f2bf(W[(k + 1) * 64 + c]);
    o.z = f2bf(W[(k + 2) * 64 + c]);
    o.w = f2bf(W[(k + 3) * 64 + c]);
    *reinterpret_cast<ushort4*>(wt + u) = o;
}

// ---------------- MFMA GEMM: S[N,64] = bf16(X[N,K] @ W[K,64]) ---------------
// Block = 64 rows, 4 waves; wave = 16 rows x 64 cols via 4x mfma 16x16x32.
// A staged [64][K+8] bf16 (pad 8 = 16B keeps b128 align, breaks bank stride);
// Wt (bf16, pre-transposed [64][K]) staged same way. Fragments (gfx950):
// A: lane row=l&15, k=(l>>4)*8..+8 ; B: lane col=l&15, same k ;
// D: col=l&15, row=(l>>4)*4+reg [m89-verified]. Epilogue restages C through
// the wave's own A-region for coalesced 16B global stores.

template <int K, typename XT>
__global__ __launch_bounds__(256) void gemm_mfma(const XT* __restrict__ X,
                                                 const ushort_t* __restrict__ Wt,
                                                 ushort_t* __restrict__ S) {
    __shared__ ushort_t A_lds[64][K + 8];
    __shared__ ushort_t B_lds[64][K + 8];

    int t = threadIdx.x;

    // stage Wt -> B_lds (coalesced b128 reads, row-linear writes)
    for (int u = t; u < 64 * K / 8; u += 256) {
        int c = u / (K / 8), seg = u % (K / 8);
        bf16x8 v = *reinterpret_cast<const bf16x8*>(Wt + c * K + seg * 8);
        *reinterpret_cast<bf16x8*>(&B_lds[c][seg * 8]) = v;
    }

    // stage X tile (64 rows, clamp at NN) -> A_lds as bf16
    int row_base = blockIdx.x * 64;
    if constexpr (sizeof(XT) == 4) {   // fp32 input: convert
        for (int u = t; u < 64 * K / 4; u += 256) {
            int r = u / (K / 4), seg = u % (K / 4);
            int g = min(row_base + r, NN - 1);
            float4 x = *reinterpret_cast<const float4*>((const float*)X + (size_t)g * K + seg * 4);
            unsigned p0 = (unsigned)f2bf(x.x) | ((unsigned)f2bf(x.y) << 16);
            unsigned p1 = (unsigned)f2bf(x.z) | ((unsigned)f2bf(x.w) << 16);
            *reinterpret_cast<uint2*>(&A_lds[r][seg * 4]) = make_uint2(p0, p1);
        }
    } else {                            // bf16 input: straight copy
        for (int u = t; u < 64 * K / 8; u += 256) {
            int r = u / (K / 8), seg = u % (K / 8);
            int g = min(row_base + r, NN - 1);
            bf16x8 v = *reinterpret_cast<const bf16x8*>((const ushort_t*)X + (size_t)g * K + seg * 8);
            *reinterpret_cast<bf16x8*>(&A_lds[r][seg * 8]) = v;
        }
    }
    __syncthreads();

    int wave = t >> 6;
    int lane = t & 63;
    int grp  = lane >> 4;     // 0..3
    int lr   = lane & 15;     // 0..15
    int arow = wave * 16 + lr;

    f32x4 acc0 = {0.f, 0.f, 0.f, 0.f};
    f32x4 acc1 = {0.f, 0.f, 0.f, 0.f};
    f32x4 acc2 = {0.f, 0.f, 0.f, 0.f};
    f32x4 acc3 = {0.f, 0.f, 0.f, 0.f};

#pragma unroll
    for (int kc = 0; kc < K / 32; ++kc) {
        int ko = kc * 32 + grp * 8;
        bf16x8 a  = *reinterpret_cast<const bf16x8*>(&A_lds[arow][ko]);
        bf16x8 b0 = *reinterpret_cast<const bf16x8*>(&B_lds[lr][ko]);
        bf16x8 b1 = *reinterpret_cast<const bf16x8*>(&B_lds[16 + lr][ko]);
        bf16x8 b2 = *reinterpret_cast<const bf16x8*>(&B_lds[32 + lr][ko]);
        bf16x8 b3 = *reinterpret_cast<const bf16x8*>(&B_lds[48 + lr][ko]);
        acc0 = __builtin_amdgcn_mfma_f32_16x16x32_bf16(a, b0, acc0, 0, 0, 0);
        acc1 = __builtin_amdgcn_mfma_f32_16x16x32_bf16(a, b1, acc1, 0, 0, 0);
        acc2 = __builtin_amdgcn_mfma_f32_16x16x32_bf16(a, b2, acc2, 0, 0, 0);
        acc3 = __builtin_amdgcn_mfma_f32_16x16x32_bf16(a, b3, acc3, 0, 0, 0);
    }

    // epilogue: restage C (bf16) into this wave's A-region, then coalesced store
#pragma unroll
    for (int r = 0; r < 4; ++r) {
        int orow = wave * 16 + grp * 4 + r;
        A_lds[orow][lr]      = f2bf(acc0[r]);
        A_lds[orow][16 + lr] = f2bf(acc1[r]);
        A_lds[orow][32 + lr] = f2bf(acc2[r]);
        A_lds[orow][48 + lr] = f2bf(acc3[r]);
    }
    // wave-local write->read: compiler inserts lgkmcnt for aliasing LDS ops
#pragma unroll
    for (int u = lane; u < 16 * 8; u += 64) {
        int r = u >> 3, sg = u & 7;
        int grow = row_base + wave * 16 + r;
        if (grow < NN) {
            bf16x8 v = *reinterpret_cast<const bf16x8*>(&A_lds[wave * 16 + r][sg * 8]);
            *reinterpret_cast<bf16x8*>(S + ((size_t)grow << 6) + sg * 8) = v;
        }
    }
}

// ---------------- SPMM gather (bf16 S; 16 loads in flight, 4 acc chains) ----

template <bool RELU, typename OT>
__global__ __launch_bounds__(256) void spmm_kernel(const int2* __restrict__ csr,
                                                   const int* __restrict__ offsets,
                                                   const ushort_t* __restrict__ S,
                                                   const float* __restrict__ bias,
                                                   OT* __restrict__ out, int N) {
    int wave = threadIdx.x >> 6;
    int lane = threadIdx.x & 63;
    int row  = blockIdx.x * 4 + wave;
    if (row >= N) return;

    int beg = offsets[row];
    int end = offsets[row + 1];
    float a0 = 0.f, a1 = 0.f, a2 = 0.f, a3 = 0.f;
    int e = beg;
    for (; e + 16 <= end; e += 16) {
        int2 c[16];
        float v[16];
#pragma unroll
        for (int i = 0; i < 16; ++i) c[i] = csr[e + i];
#pragma unroll
        for (int i = 0; i < 16; ++i) v[i] = bf2f(S[c[i].x * 64 + lane]);
#pragma unroll
        for (int i = 0; i < 16; i += 4) {
            a0 = fmaf(__int_as_float(c[i].y),     v[i],     a0);
            a1 = fmaf(__int_as_float(c[i + 1].y), v[i + 1], a1);
            a2 = fmaf(__int_as_float(c[i + 2].y), v[i + 2], a2);
            a3 = fmaf(__int_as_float(c[i + 3].y), v[i + 3], a3);
        }
    }
    for (; e + 4 <= end; e += 4) {
        int2 c0 = csr[e], c1 = csr[e + 1], c2 = csr[e + 2], c3 = csr[e + 3];
        a0 = fmaf(__int_as_float(c0.y), bf2f(S[c0.x * 64 + lane]), a0);
        a1 = fmaf(__int_as_float(c1.y), bf2f(S[c1.x * 64 + lane]), a1);
        a2 = fmaf(__int_as_float(c2.y), bf2f(S[c2.x * 64 + lane]), a2);
        a3 = fmaf(__int_as_float(c3.y), bf2f(S[c3.x * 64 + lane]), a3);
    }
    for (; e < end; ++e) {
        int2 c0 = csr[e];
        a0 = fmaf(__int_as_float(c0.y), bf2f(S[c0.x * 64 + lane]), a0);
    }
    float vv = (a0 + a1) + (a2 + a3) + bias[lane];
    if (RELU) vv = fmaxf(vv, 0.f);
    if constexpr (sizeof(OT) == 2)
        out[(size_t)row * 64 + lane] = f2bf(vv);
    else
        out[(size_t)row * 64 + lane] = vv;
}

// ---------------- launch ----------------

extern "C" void kernel_launch(void* const* d_in, const int* in_sizes, int n_in,
                              void* d_out, int out_size, void* d_ws, size_t ws_size,
                              hipStream_t stream) {
    const float* features = (const float*)d_in[0];
    const int*   src      = (const int*)d_in[1];
    const int*   dst      = (const int*)d_in[2];
    const float* ew       = (const float*)d_in[3];
    const float* W1       = (const float*)d_in[4];
    const float* b1       = (const float*)d_in[5];
    const float* W2       = (const float*)d_in[6];
    const float* b2       = (const float*)d_in[7];
    const float* W3       = (const float*)d_in[8];
    const float* b3       = (const float*)d_in[9];
    float*       out      = (float*)d_out;

    float*    s_f32  = (float*)d_ws;                     // NN*64 f32 region; S lives as bf16
    ushort_t* s_bf   = (ushort_t*)d_ws;
    float*    h_f32  = s_f32 + (size_t)NN * 64;          // NN*64 f32 region; rec & h(bf16) alias
    ushort_t* h_bf   = (ushort_t*)h_f32;
    int*   offsets = (int*)(h_f32 + (size_t)NN * 64);    // NN+4
    int*   gcnt    = offsets + NN + 4;                   // pad 512
    int*   bbase   = gcnt + 512;                         // pad 512
    int*   wcur    = bbase + 512;                        // pad 512
    ushort_t* wt1  = (ushort_t*)(wcur + 512);            // 64*128 bf16
    ushort_t* wt2  = wt1 + 64 * 128;                     // 64*64
    ushort_t* wt3  = wt2 + 64 * 64;                      // 64*64
    int2*  csr     = (int2*)(wt3 + 64 * 64);             // NE packed records
    u64*   rec     = (u64*)h_f32;                        // NE binned records (dead before spmm1)

    (void)hipMemsetAsync(gcnt, 0, NBUCK * sizeof(int), stream);
    wconv_kernel<<<16, 256, 0, stream>>>(W1, W2, W3, wt1, wt2, wt3);
    bucket_hist<<<NHB, 256, 0, stream>>>(dst, gcnt);
    bucket_scan<<<1, 512, 0, stream>>>(gcnt, bbase, wcur, offsets);
    bin_kernel<<<NTILE, 256, 0, stream>>>(src, dst, ew, wcur, rec);
    sort_kernel<<<NBUCK, 256, 0, stream>>>(rec, bbase, offsets, csr);

    int grid_gemm = (NN + 63) / 64;     // 1563
    int grid_rows = (NN + 3) / 4;       // 25000
    gemm_mfma<128, float><<<grid_gemm, 256, 0, stream>>>(features, wt1, s_bf);
    spmm_kernel<true, ushort_t><<<grid_rows, 256, 0, stream>>>(csr, offsets, s_bf, b1, h_bf, NN);
    gemm_mfma<64, ushort_t><<<grid_gemm, 256, 0, stream>>>(h_bf, wt2, s_bf);
    spmm_kernel<true, ushort_t><<<grid_rows, 256, 0, stream>>>(csr, offsets, s_bf, b2, h_bf, NN);
    gemm_mfma<64, ushort_t><<<grid_gemm, 256, 0, stream>>>(h_bf, wt3, s_bf);
    spmm_kernel<false, float><<<grid_rows, 256, 0, stream>>>(csr, offsets, s_bf, b3, out, NN);
}

// Round 14
// 262.755 us; speedup vs baseline: 1.5615x; 1.0264x over previous
//
#include <hip/hip_runtime.h>

#define NN 100000
#define NE 1600000

#define BNODES 256                          // nodes per sort bucket
#define NBUCK ((NN + BNODES - 1) / BNODES)  // 391
#define TILE 4096                           // edges per bin tile
#define NTILE ((NE + TILE - 1) / TILE)      // 391
#define CAP 5120                            // LDS sort capacity
#define HTILE 4096                          // edges per bucket_hist block
#define NHB ((NE + HTILE - 1) / HTILE)      // 391

#define RPB 16                              // rows per spmm block
#define ECAP 768                            // LDS edge cap (mean 256, ~8 sigma)

typedef unsigned long long u64;
typedef unsigned short ushort_t;
typedef __attribute__((ext_vector_type(8))) short bf16x8;
typedef __attribute__((ext_vector_type(4))) float f32x4;

// float -> bf16 RNE
__device__ __forceinline__ ushort_t f2bf(float f) {
    unsigned u = __float_as_uint(f);
    u += 0x7fffu + ((u >> 16) & 1u);
    return (ushort_t)(u >> 16);
}
__device__ __forceinline__ float bf2f(ushort_t b) {
    return __uint_as_float(((unsigned)b) << 16);
}

// ---------------- bucket histogram ----------------

__global__ __launch_bounds__(256) void bucket_hist(const int* __restrict__ dst,
                                                   int* __restrict__ gcnt) {
    __shared__ int cnt[NBUCK];
    int t = threadIdx.x;
    for (int b = t; b < NBUCK; b += 256) cnt[b] = 0;
    __syncthreads();
    int e0 = blockIdx.x * HTILE + t * 16;
    if (e0 < NE) {
#pragma unroll
        for (int q = 0; q < 4; ++q) {
            int4 d = *reinterpret_cast<const int4*>(dst + e0 + q * 4);
            atomicAdd(&cnt[d.x >> 8], 1);
            atomicAdd(&cnt[d.y >> 8], 1);
            atomicAdd(&cnt[d.z >> 8], 1);
            atomicAdd(&cnt[d.w >> 8], 1);
        }
    }
    __syncthreads();
    for (int b = t; b < NBUCK; b += 256)
        if (cnt[b]) atomicAdd(&gcnt[b], cnt[b]);
}

__global__ __launch_bounds__(512) void bucket_scan(const int* __restrict__ gcnt,
                                                   int* __restrict__ bbase,
                                                   int* __restrict__ wcur,
                                                   int* __restrict__ offsets) {
    __shared__ int tmp[512];
    int t = threadIdx.x;
    int v = (t < NBUCK) ? gcnt[t] : 0;
    tmp[t] = v;
    __syncthreads();
    for (int off = 1; off < 512; off <<= 1) {
        int u = (t >= off) ? tmp[t - off] : 0;
        __syncthreads();
        tmp[t] += u;
        __syncthreads();
    }
    if (t < NBUCK) {
        int base = tmp[t] - v;
        bbase[t] = base;
        wcur[t]  = base;
    }
    if (t == NBUCK - 1) bbase[NBUCK] = tmp[t];
    if (t == 0) offsets[NN] = NE;
}

// ---------------- phase A: bin edges into 391 buckets ----------------

__global__ __launch_bounds__(256) void bin_kernel(const int* __restrict__ src,
                                                  const int* __restrict__ dst,
                                                  const float* __restrict__ w,
                                                  int* __restrict__ wcur,
                                                  u64* __restrict__ rec) {
    __shared__ int cnt[512];
    __shared__ int base_l[512];
    __shared__ int gbase[NBUCK];
    __shared__ int lofs[NBUCK];
    __shared__ int scan2[256];
    __shared__ u64 stage[TILE];
    __shared__ unsigned short stage_b[TILE];

    int t = threadIdx.x;
    cnt[t] = 0;
    cnt[t + 256] = 0;
    for (int b = t; b < NBUCK; b += 256) lofs[b] = 0;   // strided: NBUCK > 256
    __syncthreads();

    int e0 = blockIdx.x * TILE + t * 16;
    bool valid = e0 < NE;
    int d[16], s[16];
    float ww[16];
    if (valid) {
#pragma unroll
        for (int q = 0; q < 4; ++q) {
            int4 dv = *reinterpret_cast<const int4*>(dst + e0 + q * 4);
            int4 sv = *reinterpret_cast<const int4*>(src + e0 + q * 4);
            float4 wv = *reinterpret_cast<const float4*>(w + e0 + q * 4);
            d[q * 4 + 0] = dv.x; d[q * 4 + 1] = dv.y; d[q * 4 + 2] = dv.z; d[q * 4 + 3] = dv.w;
            s[q * 4 + 0] = sv.x; s[q * 4 + 1] = sv.y; s[q * 4 + 2] = sv.z; s[q * 4 + 3] = sv.w;
            ww[q * 4 + 0] = wv.x; ww[q * 4 + 1] = wv.y; ww[q * 4 + 2] = wv.z; ww[q * 4 + 3] = wv.w;
        }
#pragma unroll
        for (int i = 0; i < 16; ++i) atomicAdd(&cnt[d[i] >> 8], 1);
    }
    __syncthreads();

    int pair = cnt[2 * t] + cnt[2 * t + 1];
    scan2[t] = pair;
    __syncthreads();
    for (int off = 1; off < 256; off <<= 1) {
        int u = (t >= off) ? scan2[t - off] : 0;
        __syncthreads();
        scan2[t] += u;
        __syncthreads();
    }
    int excl = scan2[t] - pair;
    base_l[2 * t]     = excl;
    base_l[2 * t + 1] = excl + cnt[2 * t];
    for (int b = t; b < NBUCK; b += 256)
        gbase[b] = atomicAdd(&wcur[b], cnt[b]);
    __syncthreads();

    if (valid) {
#pragma unroll
        for (int i = 0; i < 16; ++i) {
            int b = d[i] >> 8;
            int p = base_l[b] + atomicAdd(&lofs[b], 1);
            u64 hi = (u64)(unsigned)(s[i] | ((d[i] & 0xFF) << 17));
            stage[p]   = (hi << 32) | (u64)(unsigned)__float_as_int(ww[i]);
            stage_b[p] = (unsigned short)b;
        }
    }
    __syncthreads();

    int tot = scan2[255];
    for (int i = t; i < tot; i += 256) {
        int b = stage_b[i];
        rec[gbase[b] + (i - base_l[b])] = stage[i];
    }
}

// ---------------- phase B: per-bucket count+scan+sort -> offsets & CSR ------

__global__ __launch_bounds__(256) void sort_kernel(const u64* __restrict__ rec,
                                                   const int* __restrict__ bbase,
                                                   int* __restrict__ offsets,
                                                   int2* __restrict__ csr) {
    __shared__ int2 outb[CAP];
    __shared__ int scanb[BNODES];
    __shared__ int off_l[BNODES];
    __shared__ int ctr[BNODES];

    int b = blockIdx.x;
    int node0 = b << 8;
    int t = threadIdx.x;
    int gbase = bbase[b];
    int gend  = bbase[b + 1];
    int cntb  = gend - gbase;

    ctr[t] = 0;
    __syncthreads();

    for (int i = t; i < cntb; i += 256) {
        u64 r = rec[gbase + i];
        int n = (int)((unsigned)(r >> 32) >> 17);
        atomicAdd(&ctr[n], 1);
    }
    __syncthreads();

    int v = ctr[t];
    scanb[t] = v;
    __syncthreads();
    for (int off = 1; off < 256; off <<= 1) {
        int u = (t >= off) ? scanb[t - off] : 0;
        __syncthreads();
        scanb[t] += u;
        __syncthreads();
    }
    int excl = scanb[t] - v;
    off_l[t] = excl;
    ctr[t] = 0;
    int node = node0 + t;
    if (node < NN) offsets[node] = gbase + excl;
    __syncthreads();

    if (cntb <= CAP) {
        for (int i = t; i < cntb; i += 256) {
            u64 r = rec[gbase + i];
            unsigned hi = (unsigned)(r >> 32);
            int n = (int)(hi >> 17);
            int slot = off_l[n] + atomicAdd(&ctr[n], 1);
            outb[slot] = make_int2((int)(hi & 0x1FFFF), (int)(unsigned)r);
        }
        __syncthreads();
        for (int i = t; i < cntb; i += 256)
            csr[gbase + i] = outb[i];
    } else {
        for (int i = t; i < cntb; i += 256) {
            u64 r = rec[gbase + i];
            unsigned hi = (unsigned)(r >> 32);
            int n = (int)(hi >> 17);
            int slot = off_l[n] + atomicAdd(&ctr[n], 1);
            csr[gbase + slot] = make_int2((int)(hi & 0x1FFFF), (int)(unsigned)r);
        }
    }
}

// ---------------- W converter ----------------

__global__ __launch_bounds__(256) void wconv_kernel(const float* __restrict__ W1,
                                                    const float* __restrict__ W2,
                                                    const float* __restrict__ W3,
                                                    ushort_t* __restrict__ wt1,
                                                    ushort_t* __restrict__ wt2,
                                                    ushort_t* __restrict__ wt3) {
    int b = blockIdx.x;
    const float* W; ushort_t* wt; int K, bl;
    if (b < 8)       { W = W1; wt = wt1; K = 128; bl = b; }
    else if (b < 12) { W = W2; wt = wt2; K = 64;  bl = b - 8; }
    else             { W = W3; wt = wt3; K = 64;  bl = b - 12; }
    int u = (bl * 256 + threadIdx.x) * 4;
    if (u >= 64 * K) return;
    int c = u / K, k = u % K;
    ushort4 o;
    o.x = f2bf(W[(k + 0) * 64 + c]);
    o.y = f2bf(W[(k + 1) * 64 + c]);
    o.z = f2bf(W[(k + 2) * 64 + c]);
    o.w = f2bf(W[(k + 3) * 64 + c]);
    *reinterpret_cast<ushort4*>(wt + u) = o;
}

// ---------------- MFMA GEMM ----------------

template <int K, typename XT>
__global__ __launch_bounds__(256) void gemm_mfma(const XT* __restrict__ X,
                                                 const ushort_t* __restrict__ Wt,
                                                 ushort_t* __restrict__ S) {
    __shared__ ushort_t A_lds[64][K + 8];
    __shared__ ushort_t B_lds[64][K + 8];

    int t = threadIdx.x;

    for (int u = t; u < 64 * K / 8; u += 256) {
        int c = u / (K / 8), seg = u % (K / 8);
        bf16x8 v = *reinterpret_cast<const bf16x8*>(Wt + c * K + seg * 8);
        *reinterpret_cast<bf16x8*>(&B_lds[c][seg * 8]) = v;
    }

    int row_base = blockIdx.x * 64;
    if constexpr (sizeof(XT) == 4) {
        for (int u = t; u < 64 * K / 4; u += 256) {
            int r = u / (K / 4), seg = u % (K / 4);
            int g = min(row_base + r, NN - 1);
            float4 x = *reinterpret_cast<const float4*>((const float*)X + (size_t)g * K + seg * 4);
            unsigned p0 = (unsigned)f2bf(x.x) | ((unsigned)f2bf(x.y) << 16);
            unsigned p1 = (unsigned)f2bf(x.z) | ((unsigned)f2bf(x.w) << 16);
            *reinterpret_cast<uint2*>(&A_lds[r][seg * 4]) = make_uint2(p0, p1);
        }
    } else {
        for (int u = t; u < 64 * K / 8; u += 256) {
            int r = u / (K / 8), seg = u % (K / 8);
            int g = min(row_base + r, NN - 1);
            bf16x8 v = *reinterpret_cast<const bf16x8*>((const ushort_t*)X + (size_t)g * K + seg * 8);
            *reinterpret_cast<bf16x8*>(&A_lds[r][seg * 8]) = v;
        }
    }
    __syncthreads();

    int wave = t >> 6;
    int lane = t & 63;
    int grp  = lane >> 4;
    int lr   = lane & 15;
    int arow = wave * 16 + lr;

    f32x4 acc0 = {0.f, 0.f, 0.f, 0.f};
    f32x4 acc1 = {0.f, 0.f, 0.f, 0.f};
    f32x4 acc2 = {0.f, 0.f, 0.f, 0.f};
    f32x4 acc3 = {0.f, 0.f, 0.f, 0.f};

#pragma unroll
    for (int kc = 0; kc < K / 32; ++kc) {
        int ko = kc * 32 + grp * 8;
        bf16x8 a  = *reinterpret_cast<const bf16x8*>(&A_lds[arow][ko]);
        bf16x8 b0 = *reinterpret_cast<const bf16x8*>(&B_lds[lr][ko]);
        bf16x8 b1 = *reinterpret_cast<const bf16x8*>(&B_lds[16 + lr][ko]);
        bf16x8 b2 = *reinterpret_cast<const bf16x8*>(&B_lds[32 + lr][ko]);
        bf16x8 b3 = *reinterpret_cast<const bf16x8*>(&B_lds[48 + lr][ko]);
        acc0 = __builtin_amdgcn_mfma_f32_16x16x32_bf16(a, b0, acc0, 0, 0, 0);
        acc1 = __builtin_amdgcn_mfma_f32_16x16x32_bf16(a, b1, acc1, 0, 0, 0);
        acc2 = __builtin_amdgcn_mfma_f32_16x16x32_bf16(a, b2, acc2, 0, 0, 0);
        acc3 = __builtin_amdgcn_mfma_f32_16x16x32_bf16(a, b3, acc3, 0, 0, 0);
    }

#pragma unroll
    for (int r = 0; r < 4; ++r) {
        int orow = wave * 16 + grp * 4 + r;
        A_lds[orow][lr]      = f2bf(acc0[r]);
        A_lds[orow][16 + lr] = f2bf(acc1[r]);
        A_lds[orow][32 + lr] = f2bf(acc2[r]);
        A_lds[orow][48 + lr] = f2bf(acc3[r]);
    }
#pragma unroll
    for (int u = lane; u < 16 * 8; u += 64) {
        int r = u >> 3, sg = u & 7;
        int grow = row_base + wave * 16 + r;
        if (grow < NN) {
            bf16x8 v = *reinterpret_cast<const bf16x8*>(&A_lds[wave * 16 + r][sg * 8]);
            *reinterpret_cast<bf16x8*>(S + ((size_t)grow << 6) + sg * 8) = v;
        }
    }
}

// ---------------- SPMM gather: 16 rows/block, csr span staged in LDS --------
// Wave owns 4 rows, lockstep rounds of 8 edges/row -> 32 outstanding gathers
// per wave; csr reads come from LDS (broadcast, free); ok-predicates are
// wave-uniform (row ranges are per-wave scalars). Inactive slots gather
// S[lane] (row 0, L1-hot) with weight 0 - keeps control flow uniform.

template <bool RELU, typename OT>
__global__ __launch_bounds__(256) void spmm_kernel(const int2* __restrict__ csr,
                                                   const int* __restrict__ offsets,
                                                   const ushort_t* __restrict__ S,
                                                   const float* __restrict__ bias,
                                                   OT* __restrict__ out) {
    __shared__ int2 ecsr[ECAP];
    __shared__ int soff[RPB + 1];
    int t = threadIdx.x;
    int row_base = blockIdx.x * RPB;                  // NN % RPB == 0
    if (t <= RPB) soff[t] = offsets[row_base + t];
    __syncthreads();
    int sbeg = soff[0];
    int cnt  = soff[RPB] - sbeg;
    bool fits = cnt <= ECAP;
    if (fits) {
        for (int i = t; i < cnt; i += 256) ecsr[i] = csr[sbeg + i];   // coalesced
    }
    __syncthreads();

    int wave = t >> 6;
    int lane = t & 63;
    int r0 = wave * 4;
    int eb0 = soff[r0]     - sbeg, ee0 = soff[r0 + 1] - sbeg;
    int eb1 = soff[r0 + 1] - sbeg, ee1 = soff[r0 + 2] - sbeg;
    int eb2 = soff[r0 + 2] - sbeg, ee2 = soff[r0 + 3] - sbeg;
    int eb3 = soff[r0 + 3] - sbeg, ee3 = soff[r0 + 4] - sbeg;

    float b = bias[lane];
    const ushort_t* Sl = S + lane;
    float acc0 = 0.f, acc1 = 0.f, acc2 = 0.f, acc3 = 0.f;

    if (fits) {
        int rounds = max(max((ee0 - eb0 + 7) >> 3, (ee1 - eb1 + 7) >> 3),
                         max((ee2 - eb2 + 7) >> 3, (ee3 - eb3 + 7) >> 3));
        for (int rd = 0; rd < rounds; ++rd) {
            float v[4][8], wv[4][8];
            int b0 = eb0 + rd * 8, b1 = eb1 + rd * 8, b2 = eb2 + rd * 8, b3 = eb3 + rd * 8;
#pragma unroll
            for (int j = 0; j < 8; ++j) {
                int2 c0 = (b0 + j < ee0) ? ecsr[b0 + j] : make_int2(0, 0);
                int2 c1 = (b1 + j < ee1) ? ecsr[b1 + j] : make_int2(0, 0);
                int2 c2 = (b2 + j < ee2) ? ecsr[b2 + j] : make_int2(0, 0);
                int2 c3 = (b3 + j < ee3) ? ecsr[b3 + j] : make_int2(0, 0);
                wv[0][j] = __int_as_float(c0.y); v[0][j] = bf2f(Sl[c0.x << 6]);
                wv[1][j] = __int_as_float(c1.y); v[1][j] = bf2f(Sl[c1.x << 6]);
                wv[2][j] = __int_as_float(c2.y); v[2][j] = bf2f(Sl[c2.x << 6]);
                wv[3][j] = __int_as_float(c3.y); v[3][j] = bf2f(Sl[c3.x << 6]);
            }
#pragma unroll
            for (int j = 0; j < 8; ++j) {
                acc0 = fmaf(wv[0][j], v[0][j], acc0);
                acc1 = fmaf(wv[1][j], v[1][j], acc1);
                acc2 = fmaf(wv[2][j], v[2][j], acc2);
                acc3 = fmaf(wv[3][j], v[3][j], acc3);
            }
        }
    } else {
        // fallback (cnt > ECAP, ~never): direct global csr
        for (int e = sbeg + eb0; e < sbeg + ee0; ++e) { int2 c = csr[e]; acc0 = fmaf(__int_as_float(c.y), bf2f(Sl[c.x << 6]), acc0); }
        for (int e = sbeg + eb1; e < sbeg + ee1; ++e) { int2 c = csr[e]; acc1 = fmaf(__int_as_float(c.y), bf2f(Sl[c.x << 6]), acc1); }
        for (int e = sbeg + eb2; e < sbeg + ee2; ++e) { int2 c = csr[e]; acc2 = fmaf(__int_as_float(c.y), bf2f(Sl[c.x << 6]), acc2); }
        for (int e = sbeg + eb3; e < sbeg + ee3; ++e) { int2 c = csr[e]; acc3 = fmaf(__int_as_float(c.y), bf2f(Sl[c.x << 6]), acc3); }
    }

    float o0 = acc0 + b, o1 = acc1 + b, o2 = acc2 + b, o3 = acc3 + b;
    if (RELU) {
        o0 = fmaxf(o0, 0.f); o1 = fmaxf(o1, 0.f);
        o2 = fmaxf(o2, 0.f); o3 = fmaxf(o3, 0.f);
    }
    size_t base = ((size_t)(row_base + r0) << 6) + lane;
    if constexpr (sizeof(OT) == 2) {
        out[base]       = f2bf(o0);
        out[base + 64]  = f2bf(o1);
        out[base + 128] = f2bf(o2);
        out[base + 192] = f2bf(o3);
    } else {
        out[base]       = o0;
        out[base + 64]  = o1;
        out[base + 128] = o2;
        out[base + 192] = o3;
    }
}

// ---------------- launch ----------------

extern "C" void kernel_launch(void* const* d_in, const int* in_sizes, int n_in,
                              void* d_out, int out_size, void* d_ws, size_t ws_size,
                              hipStream_t stream) {
    const float* features = (const float*)d_in[0];
    const int*   src      = (const int*)d_in[1];
    const int*   dst      = (const int*)d_in[2];
    const float* ew       = (const float*)d_in[3];
    const float* W1       = (const float*)d_in[4];
    const float* b1       = (const float*)d_in[5];
    const float* W2       = (const float*)d_in[6];
    const float* b2       = (const float*)d_in[7];
    const float* W3       = (const float*)d_in[8];
    const float* b3       = (const float*)d_in[9];
    float*       out      = (float*)d_out;

    float*    s_f32  = (float*)d_ws;
    ushort_t* s_bf   = (ushort_t*)d_ws;
    float*    h_f32  = s_f32 + (size_t)NN * 64;
    ushort_t* h_bf   = (ushort_t*)h_f32;
    int*   offsets = (int*)(h_f32 + (size_t)NN * 64);
    int*   gcnt    = offsets + NN + 4;
    int*   bbase   = gcnt + 512;
    int*   wcur    = bbase + 512;
    ushort_t* wt1  = (ushort_t*)(wcur + 512);
    ushort_t* wt2  = wt1 + 64 * 128;
    ushort_t* wt3  = wt2 + 64 * 64;
    int2*  csr     = (int2*)(wt3 + 64 * 64);
    u64*   rec     = (u64*)h_f32;

    (void)hipMemsetAsync(gcnt, 0, NBUCK * sizeof(int), stream);
    wconv_kernel<<<16, 256, 0, stream>>>(W1, W2, W3, wt1, wt2, wt3);
    bucket_hist<<<NHB, 256, 0, stream>>>(dst, gcnt);
    bucket_scan<<<1, 512, 0, stream>>>(gcnt, bbase, wcur, offsets);
    bin_kernel<<<NTILE, 256, 0, stream>>>(src, dst, ew, wcur, rec);
    sort_kernel<<<NBUCK, 256, 0, stream>>>(rec, bbase, offsets, csr);

    int grid_gemm = (NN + 63) / 64;     // 1563
    int grid_spmm = NN / RPB;           // 6250
    gemm_mfma<128, float><<<grid_gemm, 256, 0, stream>>>(features, wt1, s_bf);
    spmm_kernel<true, ushort_t><<<grid_spmm, 256, 0, stream>>>(csr, offsets, s_bf, b1, h_bf);
    gemm_mfma<64, ushort_t><<<grid_gemm, 256, 0, stream>>>(h_bf, wt2, s_bf);
    spmm_kernel<true, ushort_t><<<grid_spmm, 256, 0, stream>>>(csr, offsets, s_bf, b2, h_bf);
    gemm_mfma<64, ushort_t><<<grid_gemm, 256, 0, stream>>>(h_bf, wt3, s_bf);
    spmm_kernel<false, float><<<grid_spmm, 256, 0, stream>>>(csr, offsets, s_bf, b3, out);
}

// Round 15
// 195.788 us; speedup vs baseline: 2.0956x; 1.3420x over previous
//
#include <hip/hip_runtime.h>

#define NN 100000
#define NE 1600000

#define BNODES 256                          // nodes per sort bucket
#define NBUCK ((NN + BNODES - 1) / BNODES)  // 391
#define TILE 4096                           // edges per bin tile
#define NTILE ((NE + TILE - 1) / TILE)      // 391
#define CAP 5120                            // LDS sort capacity
#define HTILE 4096                          // edges per bucket_hist block
#define NHB ((NE + HTILE - 1) / HTILE)      // 391

#define RPB 16                              // rows per spmm block
#define ECAP 768                            // LDS edge cap (mean 256, ~32 sigma)

typedef unsigned long long u64;
typedef unsigned short ushort_t;
typedef __attribute__((ext_vector_type(8))) short bf16x8;
typedef __attribute__((ext_vector_type(4))) float f32x4;

// float -> bf16 RNE
__device__ __forceinline__ ushort_t f2bf(float f) {
    unsigned u = __float_as_uint(f);
    u += 0x7fffu + ((u >> 16) & 1u);
    return (ushort_t)(u >> 16);
}
__device__ __forceinline__ float bf2f(ushort_t b) {
    return __uint_as_float(((unsigned)b) << 16);
}

// ---------------- bucket histogram ----------------

__global__ __launch_bounds__(256) void bucket_hist(const int* __restrict__ dst,
                                                   int* __restrict__ gcnt) {
    __shared__ int cnt[NBUCK];
    int t = threadIdx.x;
    for (int b = t; b < NBUCK; b += 256) cnt[b] = 0;
    __syncthreads();
    int e0 = blockIdx.x * HTILE + t * 16;
    if (e0 < NE) {
#pragma unroll
        for (int q = 0; q < 4; ++q) {
            int4 d = *reinterpret_cast<const int4*>(dst + e0 + q * 4);
            atomicAdd(&cnt[d.x >> 8], 1);
            atomicAdd(&cnt[d.y >> 8], 1);
            atomicAdd(&cnt[d.z >> 8], 1);
            atomicAdd(&cnt[d.w >> 8], 1);
        }
    }
    __syncthreads();
    for (int b = t; b < NBUCK; b += 256)
        if (cnt[b]) atomicAdd(&gcnt[b], cnt[b]);
}

__global__ __launch_bounds__(512) void bucket_scan(const int* __restrict__ gcnt,
                                                   int* __restrict__ bbase,
                                                   int* __restrict__ wcur,
                                                   int* __restrict__ offsets) {
    __shared__ int tmp[512];
    int t = threadIdx.x;
    int v = (t < NBUCK) ? gcnt[t] : 0;
    tmp[t] = v;
    __syncthreads();
    for (int off = 1; off < 512; off <<= 1) {
        int u = (t >= off) ? tmp[t - off] : 0;
        __syncthreads();
        tmp[t] += u;
        __syncthreads();
    }
    if (t < NBUCK) {
        int base = tmp[t] - v;
        bbase[t] = base;
        wcur[t]  = base;
    }
    if (t == NBUCK - 1) bbase[NBUCK] = tmp[t];
    if (t == 0) offsets[NN] = NE;
}

// ---------------- phase A: bin edges into 391 buckets ----------------

__global__ __launch_bounds__(256) void bin_kernel(const int* __restrict__ src,
                                                  const int* __restrict__ dst,
                                                  const float* __restrict__ w,
                                                  int* __restrict__ wcur,
                                                  u64* __restrict__ rec) {
    __shared__ int cnt[512];
    __shared__ int base_l[512];
    __shared__ int gbase[NBUCK];
    __shared__ int lofs[NBUCK];
    __shared__ int scan2[256];
    __shared__ u64 stage[TILE];
    __shared__ unsigned short stage_b[TILE];

    int t = threadIdx.x;
    cnt[t] = 0;
    cnt[t + 256] = 0;
    for (int b = t; b < NBUCK; b += 256) lofs[b] = 0;   // strided: NBUCK > 256
    __syncthreads();

    int e0 = blockIdx.x * TILE + t * 16;
    bool valid = e0 < NE;
    int d[16], s[16];
    float ww[16];
    if (valid) {
#pragma unroll
        for (int q = 0; q < 4; ++q) {
            int4 dv = *reinterpret_cast<const int4*>(dst + e0 + q * 4);
            int4 sv = *reinterpret_cast<const int4*>(src + e0 + q * 4);
            float4 wv = *reinterpret_cast<const float4*>(w + e0 + q * 4);
            d[q * 4 + 0] = dv.x; d[q * 4 + 1] = dv.y; d[q * 4 + 2] = dv.z; d[q * 4 + 3] = dv.w;
            s[q * 4 + 0] = sv.x; s[q * 4 + 1] = sv.y; s[q * 4 + 2] = sv.z; s[q * 4 + 3] = sv.w;
            ww[q * 4 + 0] = wv.x; ww[q * 4 + 1] = wv.y; ww[q * 4 + 2] = wv.z; ww[q * 4 + 3] = wv.w;
        }
#pragma unroll
        for (int i = 0; i < 16; ++i) atomicAdd(&cnt[d[i] >> 8], 1);
    }
    __syncthreads();

    int pair = cnt[2 * t] + cnt[2 * t + 1];
    scan2[t] = pair;
    __syncthreads();
    for (int off = 1; off < 256; off <<= 1) {
        int u = (t >= off) ? scan2[t - off] : 0;
        __syncthreads();
        scan2[t] += u;
        __syncthreads();
    }
    int excl = scan2[t] - pair;
    base_l[2 * t]     = excl;
    base_l[2 * t + 1] = excl + cnt[2 * t];
    for (int b = t; b < NBUCK; b += 256)
        gbase[b] = atomicAdd(&wcur[b], cnt[b]);
    __syncthreads();

    if (valid) {
#pragma unroll
        for (int i = 0; i < 16; ++i) {
            int b = d[i] >> 8;
            int p = base_l[b] + atomicAdd(&lofs[b], 1);
            u64 hi = (u64)(unsigned)(s[i] | ((d[i] & 0xFF) << 17));
            stage[p]   = (hi << 32) | (u64)(unsigned)__float_as_int(ww[i]);
            stage_b[p] = (unsigned short)b;
        }
    }
    __syncthreads();

    int tot = scan2[255];
    for (int i = t; i < tot; i += 256) {
        int b = stage_b[i];
        rec[gbase[b] + (i - base_l[b])] = stage[i];
    }
}

// ---------------- phase B: per-bucket count+scan+sort -> offsets & CSR ------

__global__ __launch_bounds__(256) void sort_kernel(const u64* __restrict__ rec,
                                                   const int* __restrict__ bbase,
                                                   int* __restrict__ offsets,
                                                   int2* __restrict__ csr) {
    __shared__ int2 outb[CAP];
    __shared__ int scanb[BNODES];
    __shared__ int off_l[BNODES];
    __shared__ int ctr[BNODES];

    int b = blockIdx.x;
    int node0 = b << 8;
    int t = threadIdx.x;
    int gbase = bbase[b];
    int gend  = bbase[b + 1];
    int cntb  = gend - gbase;

    ctr[t] = 0;
    __syncthreads();

    for (int i = t; i < cntb; i += 256) {
        u64 r = rec[gbase + i];
        int n = (int)((unsigned)(r >> 32) >> 17);
        atomicAdd(&ctr[n], 1);
    }
    __syncthreads();

    int v = ctr[t];
    scanb[t] = v;
    __syncthreads();
    for (int off = 1; off < 256; off <<= 1) {
        int u = (t >= off) ? scanb[t - off] : 0;
        __syncthreads();
        scanb[t] += u;
        __syncthreads();
    }
    int excl = scanb[t] - v;
    off_l[t] = excl;
    ctr[t] = 0;
    int node = node0 + t;
    if (node < NN) offsets[node] = gbase + excl;
    __syncthreads();

    if (cntb <= CAP) {
        for (int i = t; i < cntb; i += 256) {
            u64 r = rec[gbase + i];
            unsigned hi = (unsigned)(r >> 32);
            int n = (int)(hi >> 17);
            int slot = off_l[n] + atomicAdd(&ctr[n], 1);
            outb[slot] = make_int2((int)(hi & 0x1FFFF), (int)(unsigned)r);
        }
        __syncthreads();
        for (int i = t; i < cntb; i += 256)
            csr[gbase + i] = outb[i];
    } else {
        for (int i = t; i < cntb; i += 256) {
            u64 r = rec[gbase + i];
            unsigned hi = (unsigned)(r >> 32);
            int n = (int)(hi >> 17);
            int slot = off_l[n] + atomicAdd(&ctr[n], 1);
            csr[gbase + slot] = make_int2((int)(hi & 0x1FFFF), (int)(unsigned)r);
        }
    }
}

// ---------------- W converter ----------------

__global__ __launch_bounds__(256) void wconv_kernel(const float* __restrict__ W1,
                                                    const float* __restrict__ W2,
                                                    const float* __restrict__ W3,
                                                    ushort_t* __restrict__ wt1,
                                                    ushort_t* __restrict__ wt2,
                                                    ushort_t* __restrict__ wt3) {
    int b = blockIdx.x;
    const float* W; ushort_t* wt; int K, bl;
    if (b < 8)       { W = W1; wt = wt1; K = 128; bl = b; }
    else if (b < 12) { W = W2; wt = wt2; K = 64;  bl = b - 8; }
    else             { W = W3; wt = wt3; K = 64;  bl = b - 12; }
    int u = (bl * 256 + threadIdx.x) * 4;
    if (u >= 64 * K) return;
    int c = u / K, k = u % K;
    ushort4 o;
    o.x = f2bf(W[(k + 0) * 64 + c]);
    o.y = f2bf(W[(k + 1) * 64 + c]);
    o.z = f2bf(W[(k + 2) * 64 + c]);
    o.w = f2bf(W[(k + 3) * 64 + c]);
    *reinterpret_cast<ushort4*>(wt + u) = o;
}

// ---------------- MFMA GEMM ----------------

template <int K, typename XT>
__global__ __launch_bounds__(256) void gemm_mfma(const XT* __restrict__ X,
                                                 const ushort_t* __restrict__ Wt,
                                                 ushort_t* __restrict__ S) {
    __shared__ ushort_t A_lds[64][K + 8];
    __shared__ ushort_t B_lds[64][K + 8];

    int t = threadIdx.x;

    for (int u = t; u < 64 * K / 8; u += 256) {
        int c = u / (K / 8), seg = u % (K / 8);
        bf16x8 v = *reinterpret_cast<const bf16x8*>(Wt + c * K + seg * 8);
        *reinterpret_cast<bf16x8*>(&B_lds[c][seg * 8]) = v;
    }

    int row_base = blockIdx.x * 64;
    if constexpr (sizeof(XT) == 4) {
        for (int u = t; u < 64 * K / 4; u += 256) {
            int r = u / (K / 4), seg = u % (K / 4);
            int g = min(row_base + r, NN - 1);
            float4 x = *reinterpret_cast<const float4*>((const float*)X + (size_t)g * K + seg * 4);
            unsigned p0 = (unsigned)f2bf(x.x) | ((unsigned)f2bf(x.y) << 16);
            unsigned p1 = (unsigned)f2bf(x.z) | ((unsigned)f2bf(x.w) << 16);
            *reinterpret_cast<uint2*>(&A_lds[r][seg * 4]) = make_uint2(p0, p1);
        }
    } else {
        for (int u = t; u < 64 * K / 8; u += 256) {
            int r = u / (K / 8), seg = u % (K / 8);
            int g = min(row_base + r, NN - 1);
            bf16x8 v = *reinterpret_cast<const bf16x8*>((const ushort_t*)X + (size_t)g * K + seg * 8);
            *reinterpret_cast<bf16x8*>(&A_lds[r][seg * 8]) = v;
        }
    }
    __syncthreads();

    int wave = t >> 6;
    int lane = t & 63;
    int grp  = lane >> 4;
    int lr   = lane & 15;
    int arow = wave * 16 + lr;

    f32x4 acc0 = {0.f, 0.f, 0.f, 0.f};
    f32x4 acc1 = {0.f, 0.f, 0.f, 0.f};
    f32x4 acc2 = {0.f, 0.f, 0.f, 0.f};
    f32x4 acc3 = {0.f, 0.f, 0.f, 0.f};

#pragma unroll
    for (int kc = 0; kc < K / 32; ++kc) {
        int ko = kc * 32 + grp * 8;
        bf16x8 a  = *reinterpret_cast<const bf16x8*>(&A_lds[arow][ko]);
        bf16x8 b0 = *reinterpret_cast<const bf16x8*>(&B_lds[lr][ko]);
        bf16x8 b1 = *reinterpret_cast<const bf16x8*>(&B_lds[16 + lr][ko]);
        bf16x8 b2 = *reinterpret_cast<const bf16x8*>(&B_lds[32 + lr][ko]);
        bf16x8 b3 = *reinterpret_cast<const bf16x8*>(&B_lds[48 + lr][ko]);
        acc0 = __builtin_amdgcn_mfma_f32_16x16x32_bf16(a, b0, acc0, 0, 0, 0);
        acc1 = __builtin_amdgcn_mfma_f32_16x16x32_bf16(a, b1, acc1, 0, 0, 0);
        acc2 = __builtin_amdgcn_mfma_f32_16x16x32_bf16(a, b2, acc2, 0, 0, 0);
        acc3 = __builtin_amdgcn_mfma_f32_16x16x32_bf16(a, b3, acc3, 0, 0, 0);
    }

#pragma unroll
    for (int r = 0; r < 4; ++r) {
        int orow = wave * 16 + grp * 4 + r;
        A_lds[orow][lr]      = f2bf(acc0[r]);
        A_lds[orow][16 + lr] = f2bf(acc1[r]);
        A_lds[orow][32 + lr] = f2bf(acc2[r]);
        A_lds[orow][48 + lr] = f2bf(acc3[r]);
    }
#pragma unroll
    for (int u = lane; u < 16 * 8; u += 64) {
        int r = u >> 3, sg = u & 7;
        int grow = row_base + wave * 16 + r;
        if (grow < NN) {
            bf16x8 v = *reinterpret_cast<const bf16x8*>(&A_lds[wave * 16 + r][sg * 8]);
            *reinterpret_cast<bf16x8*>(S + ((size_t)grow << 6) + sg * 8) = v;
        }
    }
}

// ---------------- SPMM gather: 4 edges per VMEM instruction -----------------
// 16 lanes cover one S row (8B = 4 cols each) -> one ushort4 load fetches 4
// edges. Wave owns 4 rows; per round each row advances 4 edges => 16 edges
// in flight per VMEM issue burst at acc[4][4]=16 VGPR (occupancy back up).
// csr staged in LDS (R14), weights via 8B LDS broadcast. Epilogue: shfl_xor
// over the 4 edge-groups, lanes 0..15 store 4 cols each.

template <bool RELU, typename OT>
__global__ __launch_bounds__(256) void spmm_kernel(const int2* __restrict__ csr,
                                                   const int* __restrict__ offsets,
                                                   const ushort_t* __restrict__ S,
                                                   const float* __restrict__ bias,
                                                   OT* __restrict__ out) {
    __shared__ int2 ecsr[ECAP];
    __shared__ int soff[RPB + 1];
    int t = threadIdx.x;
    int row_base = blockIdx.x * RPB;                  // NN % RPB == 0
    if (t <= RPB) soff[t] = offsets[row_base + t];
    __syncthreads();
    int sbeg = soff[0];
    int cnt  = soff[RPB] - sbeg;
    bool fits = cnt <= ECAP;
    if (fits) {
        for (int i = t; i < cnt; i += 256) ecsr[i] = csr[sbeg + i];   // coalesced
    }
    __syncthreads();

    int wave = t >> 6;
    int lane = t & 63;
    int g    = lane >> 4;        // edge slot within round (0..3)
    int cl   = (lane & 15) * 4;  // this lane's 4 columns
    int r0   = wave * 4;

    int eb[4], ee[4];
#pragma unroll
    for (int r = 0; r < 4; ++r) {
        eb[r] = soff[r0 + r] - sbeg;
        ee[r] = soff[r0 + r + 1] - sbeg;
    }

    float acc[4][4] = {{0.f}};

    if (cnt > 0) {
        int rounds = 0;
#pragma unroll
        for (int r = 0; r < 4; ++r) rounds = max(rounds, (ee[r] - eb[r] + 3) >> 2);

        if (fits) {
            for (int rd = 0; rd < rounds; ++rd) {
#pragma unroll
                for (int r = 0; r < 4; ++r) {
                    int ei = eb[r] + rd * 4 + g;
                    bool ok = ei < ee[r];
                    int2 c = ecsr[ok ? ei : 0];
                    float wt = ok ? __int_as_float(c.y) : 0.f;
                    uint2 sv = *reinterpret_cast<const uint2*>(S + ((size_t)c.x << 6) + cl);
                    acc[r][0] = fmaf(wt, __uint_as_float(sv.x << 16), acc[r][0]);
                    acc[r][1] = fmaf(wt, __uint_as_float(sv.x & 0xffff0000u), acc[r][1]);
                    acc[r][2] = fmaf(wt, __uint_as_float(sv.y << 16), acc[r][2]);
                    acc[r][3] = fmaf(wt, __uint_as_float(sv.y & 0xffff0000u), acc[r][3]);
                }
            }
        } else {
            for (int rd = 0; rd < rounds; ++rd) {
#pragma unroll
                for (int r = 0; r < 4; ++r) {
                    int ei = eb[r] + rd * 4 + g;
                    bool ok = ei < ee[r];
                    int2 c = csr[sbeg + (ok ? ei : 0)];
                    float wt = ok ? __int_as_float(c.y) : 0.f;
                    uint2 sv = *reinterpret_cast<const uint2*>(S + ((size_t)c.x << 6) + cl);
                    acc[r][0] = fmaf(wt, __uint_as_float(sv.x << 16), acc[r][0]);
                    acc[r][1] = fmaf(wt, __uint_as_float(sv.x & 0xffff0000u), acc[r][1]);
                    acc[r][2] = fmaf(wt, __uint_as_float(sv.y << 16), acc[r][2]);
                    acc[r][3] = fmaf(wt, __uint_as_float(sv.y & 0xffff0000u), acc[r][3]);
                }
            }
        }
    }

    // reduce the 4 edge-groups (lane bits 4,5)
#pragma unroll
    for (int r = 0; r < 4; ++r)
#pragma unroll
        for (int j = 0; j < 4; ++j) {
            acc[r][j] += __shfl_xor(acc[r][j], 16);
            acc[r][j] += __shfl_xor(acc[r][j], 32);
        }

    if (lane < 16) {
        float4 bv = *reinterpret_cast<const float4*>(bias + cl);
#pragma unroll
        for (int r = 0; r < 4; ++r) {
            float o0 = acc[r][0] + bv.x, o1 = acc[r][1] + bv.y;
            float o2 = acc[r][2] + bv.z, o3 = acc[r][3] + bv.w;
            if (RELU) {
                o0 = fmaxf(o0, 0.f); o1 = fmaxf(o1, 0.f);
                o2 = fmaxf(o2, 0.f); o3 = fmaxf(o3, 0.f);
            }
            size_t base = ((size_t)(row_base + r0 + r) << 6) + cl;
            if constexpr (sizeof(OT) == 2) {
                ushort4 o;
                o.x = f2bf(o0); o.y = f2bf(o1); o.z = f2bf(o2); o.w = f2bf(o3);
                *reinterpret_cast<ushort4*>((ushort_t*)out + base) = o;
            } else {
                *reinterpret_cast<float4*>((float*)out + base) = make_float4(o0, o1, o2, o3);
            }
        }
    }
}

// ---------------- launch ----------------

extern "C" void kernel_launch(void* const* d_in, const int* in_sizes, int n_in,
                              void* d_out, int out_size, void* d_ws, size_t ws_size,
                              hipStream_t stream) {
    const float* features = (const float*)d_in[0];
    const int*   src      = (const int*)d_in[1];
    const int*   dst      = (const int*)d_in[2];
    const float* ew       = (const float*)d_in[3];
    const float* W1       = (const float*)d_in[4];
    const float* b1       = (const float*)d_in[5];
    const float* W2       = (const float*)d_in[6];
    const float* b2       = (const float*)d_in[7];
    const float* W3       = (const float*)d_in[8];
    const float* b3       = (const float*)d_in[9];
    float*       out      = (float*)d_out;

    float*    s_f32  = (float*)d_ws;
    ushort_t* s_bf   = (ushort_t*)d_ws;
    float*    h_f32  = s_f32 + (size_t)NN * 64;
    ushort_t* h_bf   = (ushort_t*)h_f32;
    int*   offsets = (int*)(h_f32 + (size_t)NN * 64);
    int*   gcnt    = offsets + NN + 4;
    int*   bbase   = gcnt + 512;
    int*   wcur    = bbase + 512;
    ushort_t* wt1  = (ushort_t*)(wcur + 512);
    ushort_t* wt2  = wt1 + 64 * 128;
    ushort_t* wt3  = wt2 + 64 * 64;
    int2*  csr     = (int2*)(wt3 + 64 * 64);
    u64*   rec     = (u64*)h_f32;

    (void)hipMemsetAsync(gcnt, 0, NBUCK * sizeof(int), stream);
    wconv_kernel<<<16, 256, 0, stream>>>(W1, W2, W3, wt1, wt2, wt3);
    bucket_hist<<<NHB, 256, 0, stream>>>(dst, gcnt);
    bucket_scan<<<1, 512, 0, stream>>>(gcnt, bbase, wcur, offsets);
    bin_kernel<<<NTILE, 256, 0, stream>>>(src, dst, ew, wcur, rec);
    sort_kernel<<<NBUCK, 256, 0, stream>>>(rec, bbase, offsets, csr);

    int grid_gemm = (NN + 63) / 64;     // 1563
    int grid_spmm = NN / RPB;           // 6250
    gemm_mfma<128, float><<<grid_gemm, 256, 0, stream>>>(features, wt1, s_bf);
    spmm_kernel<true, ushort_t><<<grid_spmm, 256, 0, stream>>>(csr, offsets, s_bf, b1, h_bf);
    gemm_mfma<64, ushort_t><<<grid_gemm, 256, 0, stream>>>(h_bf, wt2, s_bf);
    spmm_kernel<true, ushort_t><<<grid_spmm, 256, 0, stream>>>(csr, offsets, s_bf, b2, h_bf);
    gemm_mfma<64, ushort_t><<<grid_gemm, 256, 0, stream>>>(h_bf, wt3, s_bf);
    spmm_kernel<false, float><<<grid_spmm, 256, 0, stream>>>(csr, offsets, s_bf, b3, out);
}